// Round 2
// baseline (116.641 us; speedup 1.0000x reference)
//
#include <hip/hip_runtime.h>

#define IN_DIM  2048
#define OUT_DIM 4096

typedef float     f32x4 __attribute__((ext_vector_type(4)));
typedef long long llx2  __attribute__((ext_vector_type(2)));

// pack 4 fp32 -> 4 fp8 e4m3 (RNE, HW)
__device__ __forceinline__ unsigned int pk4(float a, float b, float c, float d) {
    int v = __builtin_amdgcn_cvt_pk_fp8_f32(a, b, 0, false);   // bytes 0-1
    v     = __builtin_amdgcn_cvt_pk_fp8_f32(c, d, v, true);    // bytes 2-3
    return (unsigned int)v;
}

// async global->LDS, 16B/lane; LDS dest must be wave-uniform base + lane*16
__device__ __forceinline__ void async16(const void* g, void* l) {
    __builtin_amdgcn_global_load_lds(
        (const __attribute__((address_space(1))) unsigned int*)g,
        (__attribute__((address_space(3))) unsigned int*)l,
        16, 0, 0);
}

// k-interleaved fp8 row layout: within each 64B-aligned k-block, memory
// 8B-granule g holds logical k-chunk c(g) = (g>>1) + 4*(g&1); inverse
// g(c) = 2*(c&3)+(c>>2).  => 16B position p holds chunks {p, p+4}, i.e. the
// (kk=0,qd=p) and (kk=1,qd=p) fragments: one ds_read_b128 = 2 fp8 fragments.
__device__ __forceinline__ int gmem_of(int c) { return 2 * (c & 3) + (c >> 2); }

// --------------------------------------------------------------------------
// Kernel 1: fused prep (unchanged; ~12 us, near HBM floor).
// --------------------------------------------------------------------------
extern "C" __global__ __launch_bounds__(256) void prep(
        const float* __restrict__ W, const float* __restrict__ x,
        unsigned char* __restrict__ protos, unsigned char* __restrict__ xb,
        float* __restrict__ psq_part, float* __restrict__ x_sq) {
    __shared__ float tile[64][65];   // [d][c], +1 pad (z==2 uses [0][0..3])
    const int t = threadIdx.x;

    if (blockIdx.z == 2) {
        const int b = blockIdx.x + 32 * blockIdx.y;
        const float* xp = x + (size_t)b * IN_DIM + t * 8;
        const float4 v0 = ((const float4*)xp)[0];
        const float4 v1 = ((const float4*)xp)[1];
        uint2 pk;
        pk.x = pk4(v0.x, v0.y, v0.z, v0.w);
        pk.y = pk4(v1.x, v1.y, v1.z, v1.w);
        // t*8 elems = k-block t>>3, chunk t&7 -> interleaved granule position
        *(uint2*)(xb + (size_t)b * IN_DIM + (t >> 3) * 64 + gmem_of(t & 7) * 8) = pk;

        float s = v0.x * v0.x + v0.y * v0.y + v0.z * v0.z + v0.w * v0.w
                + v1.x * v1.x + v1.y * v1.y + v1.z * v1.z + v1.w * v1.w;
#pragma unroll
        for (int off = 32; off > 0; off >>= 1) s += __shfl_down(s, off);
        const int lane = t & 63, w = t >> 6;
        if (lane == 0) tile[0][w] = s;
        __syncthreads();
        if (t == 0) x_sq[b] = tile[0][0] + tile[0][1] + tile[0][2] + tile[0][3];
        return;
    }

    const int r  = blockIdx.z;
    const int c0 = blockIdx.x * 64;
    const int d0 = blockIdx.y * 64;
    const int g  = t >> 4;
    const int cc = (t & 15) * 4;

    const float* Wp = W + (size_t)(r * IN_DIM + d0 + g) * IN_DIM + c0 + cc;
#pragma unroll
    for (int p = 0; p < 4; ++p) {
        const float4 v = *(const float4*)(Wp + (size_t)(16 * p) * IN_DIM);
        const int dl = g + 16 * p;
        tile[dl][cc]     = v.x;
        tile[dl][cc + 1] = v.y;
        tile[dl][cc + 2] = v.z;
        tile[dl][cc + 3] = v.w;
    }
    __syncthreads();

    const int c8 = t & 7;                 // k-chunk within the 64-d tile
    const int gm = gmem_of(c8);
#pragma unroll
    for (int p = 0; p < 2; ++p) {
        const int cr = (t >> 3) + 32 * p; // c-row 0..63
        float v[8];
        float ss = 0.f;
#pragma unroll
        for (int j = 0; j < 8; ++j) {     // banks (8c8+j+cr)%32 -> 2-way, free
            v[j] = tile[8 * c8 + j][cr];
            ss += v[j] * v[j];
        }
        const int o = 2 * (c0 + cr) + r;
        uint2 pk;
        pk.x = pk4(16.f * v[0], 16.f * v[1], 16.f * v[2], 16.f * v[3]);
        pk.y = pk4(16.f * v[4], 16.f * v[5], 16.f * v[6], 16.f * v[7]);
        *(uint2*)(protos + (size_t)o * IN_DIM + d0 + gm * 8) = pk;
        ss += __shfl_xor(ss, 1);
        ss += __shfl_xor(ss, 2);
        ss += __shfl_xor(ss, 4);
        if (c8 == 0) psq_part[(size_t)blockIdx.y * OUT_DIM + o] = ss;
    }
}

// --------------------------------------------------------------------------
// Kernel 2: fp8 GEMM + epilogue.
// R9/R10: T3/T4-minimum pipeline (double-buffered LDS + prefetch-ahead +
// counted s_waitcnt vmcnt(4) + raw s_barrier). The old single-buffer loop
// issued 4 global_load_lds then __syncthreads() -> s_waitcnt vmcnt(0)
// before s_barrier -> full L2/HBM latency exposed each of the 16 K-iters
// (MfmaUtil ~14%). Now tile t+1's loads stay in flight across tile t's
// compute; only vmcnt(4) (current tile's loads) is waited.
// Safety audit: no divergent barriers; prefetch into buffer nb lands only
// after all waves' reads of nb completed (ds_read results consumed by MFMA
// before the 2nd s_barrier); sched_barrier(0) after each barrier blocks
// MFMA/ds_read hoisting past the inline-asm waits (rule #18) and keeps
// epilogue vmem out of the counted region.
// LDS 32 KB (2 x 16 KB buffers) -> still 4 blocks/CU with (256,4).
// --------------------------------------------------------------------------
extern "C" __global__ __launch_bounds__(256, 4) void gemm_epi(
        const unsigned char* __restrict__ A,
        const unsigned char* __restrict__ Bt,
        const float* __restrict__ x_sq,
        const float* __restrict__ psq_part,
        const float* __restrict__ bias,
        float* __restrict__ out) {
    __shared__ __align__(16) unsigned char smem[32768];
    // buffer bb at smem+bb, bb in {0,16384}: A = [0,8192), B = [8192,16384)

    const int lid = blockIdx.x;          // XCD swizzle: XCD k owns n-tiles [8k,8k+8)
    const int xcd = lid & 7;
    const int wi  = lid >> 3;
    const int nt  = xcd * 8 + (wi & 7);
    const int mt  = wi >> 3;
    const int m0 = mt * 64;
    const int n0 = nt * 64;

    const int t = threadIdx.x;
    // staging: thread t owns LDS bytes [16t,16t+16) and [4096+16t,+16) of
    // each half. off -> row=off>>7, phys pos p=(off>>4)&7; logical l = p^(row&7);
    // l -> k-half l>>2, 16B-chunk l&3 of the row's 64B k-block.
    const int rS = t >> 3;               // row 0..31 (2nd chunk: +32, same &7)
    const int pS = t & 7;
    const int lS = pS ^ (rS & 7);
    const size_t goff = (size_t)(lS >> 2) * 1024 + (lS & 3) * 16;
    const unsigned char* gA0 = A  + (size_t)(m0 + rS) * IN_DIM + goff;
    const unsigned char* gA1 = gA0 + (size_t)32 * IN_DIM;
    const unsigned char* gB0 = Bt + (size_t)(n0 + rS) * IN_DIM + goff;
    const unsigned char* gB1 = gB0 + (size_t)32 * IN_DIM;

    const int wave = t >> 6;
    const int lane = t & 63;
    const int kh = wave & 1;             // K-half this wave owns
    const int nh = wave >> 1;            // N-half this wave owns
    const int ln = lane & 15;
    const int qd = lane >> 4;
    const int pr = (kh * 4 + qd) ^ (ln & 7);   // phys 16B pos for frag reads

    f32x4 acc[4][2] = {};

    // prologue: stage tile 0 into buffer 0
    async16(gA0, smem + t * 16);
    async16(gA1, smem + 4096 + t * 16);
    async16(gB0, smem + 8192 + t * 16);
    async16(gB1, smem + 12288 + t * 16);
    gA0 += 64; gA1 += 64; gB0 += 64; gB1 += 64;

    int bb = 0;
    for (int it = 0; it < 16; ++it) {    // BK=64 per half per iter
        const int nb = bb ^ 16384;
        if (it < 15) {
            // prefetch tile it+1 into the other buffer (safe: that buffer's
            // reads finished before the previous iteration's 2nd barrier)
            async16(gA0, smem + nb + t * 16);
            async16(gA1, smem + nb + 4096 + t * 16);
            async16(gB0, smem + nb + 8192 + t * 16);
            async16(gB1, smem + nb + 12288 + t * 16);
            gA0 += 64; gA1 += 64; gB0 += 64; gB1 += 64;
            asm volatile("s_waitcnt vmcnt(4)" ::: "memory");  // cur's 4 landed
        } else {
            asm volatile("s_waitcnt vmcnt(0)" ::: "memory");  // last tile
        }
        __builtin_amdgcn_s_barrier();        // all waves' cur stores visible
        __builtin_amdgcn_sched_barrier(0);

        const unsigned char* lA = smem + bb;
        const unsigned char* lB = smem + bb + 8192;
        llx2 af[4], bf[2];
#pragma unroll
        for (int i = 0; i < 4; ++i)
            af[i] = *(const llx2*)(lA + (i * 16 + ln) * 128 + pr * 16);
#pragma unroll
        for (int j = 0; j < 2; ++j)
            bf[j] = *(const llx2*)(lB + (nh * 32 + j * 16 + ln) * 128 + pr * 16);
#pragma unroll
        for (int kk = 0; kk < 2; ++kk)
#pragma unroll
            for (int i = 0; i < 4; ++i)
#pragma unroll
                for (int j = 0; j < 2; ++j)
                    acc[i][j] = __builtin_amdgcn_mfma_f32_16x16x32_fp8_fp8(
                                    af[i][kk], bf[j][kk], acc[i][j], 0, 0, 0);
        __builtin_amdgcn_s_barrier();        // reads done before buffer reuse
        __builtin_amdgcn_sched_barrier(0);
        bb = nb;
    }

    // cross-K-half reduction: kh=1 waves dump acc to LDS, kh=0 waves finish.
    if (kh == 1) {
#pragma unroll
        for (int i = 0; i < 4; ++i)
#pragma unroll
            for (int j = 0; j < 2; ++j)
                *(f32x4*)(smem + nh * 8192 + (i * 2 + j) * 1024 + lane * 16) =
                    acc[i][j];
    }
    __syncthreads();
    if (kh == 0) {
#pragma unroll
        for (int j = 0; j < 2; ++j) {
            const int col = n0 + nh * 32 + j * 16 + ln;
            float pb = bias[col];
#pragma unroll
            for (int dt = 0; dt < 32; ++dt)
                pb += psq_part[(size_t)dt * OUT_DIM + col];
#pragma unroll
            for (int i = 0; i < 4; ++i) {
                const f32x4 o4 = *(const f32x4*)(smem + nh * 8192 +
                                                 (i * 2 + j) * 1024 + lane * 16);
                const int row0 = m0 + i * 16 + qd * 4;
#pragma unroll
                for (int rr = 0; rr < 4; ++rr) {
                    const int row = row0 + rr;
                    out[(size_t)row * OUT_DIM + col] =
                        0.125f * (acc[i][j][rr] + o4[rr]) - x_sq[row] - pb;
                }
            }
        }
    }
}

// --------------------------------------------------------------------------
extern "C" void kernel_launch(void* const* d_in, const int* in_sizes, int n_in,
                              void* d_out, int out_size, void* d_ws, size_t ws_size,
                              hipStream_t stream) {
    const float* x    = (const float*)d_in[0];   // [1024, 2048]
    const float* W    = (const float*)d_in[1];   // [4096, 2048]
    const float* bias = (const float*)d_in[2];   // [4096]
    float* out = (float*)d_out;

    char* ws = (char*)d_ws;
    unsigned char* protos = (unsigned char*)ws;                               // 8 MB
    unsigned char* xb     = (unsigned char*)(ws + (size_t)8 * 1024 * 1024);   // 2 MB
    float* x_sq           = (float*)(ws + (size_t)10 * 1024 * 1024);          // 4 KB
    float* psq_part       = (float*)(ws + (size_t)10 * 1024 * 1024 + 65536);  // 512 KB

    prep<<<dim3(32, 32, 3), 256, 0, stream>>>(W, x, protos, xb, psq_part, x_sq);
    gemm_epi<<<dim3(1024), 256, 0, stream>>>(xb, protos, x_sq, psq_part, bias, out);
}

// Round 3
// 115.175 us; speedup vs baseline: 1.0127x; 1.0127x over previous
//
#include <hip/hip_runtime.h>

#define IN_DIM  2048
#define OUT_DIM 4096

typedef float     f32x4 __attribute__((ext_vector_type(4)));
typedef long long llx2  __attribute__((ext_vector_type(2)));

// pack 4 fp32 -> 4 fp8 e4m3 (RNE, HW)
__device__ __forceinline__ unsigned int pk4(float a, float b, float c, float d) {
    int v = __builtin_amdgcn_cvt_pk_fp8_f32(a, b, 0, false);   // bytes 0-1
    v     = __builtin_amdgcn_cvt_pk_fp8_f32(c, d, v, true);    // bytes 2-3
    return (unsigned int)v;
}

// async global->LDS, 16B/lane; LDS dest must be wave-uniform base + lane*16
__device__ __forceinline__ void async16(const void* g, void* l) {
    __builtin_amdgcn_global_load_lds(
        (const __attribute__((address_space(1))) unsigned int*)g,
        (__attribute__((address_space(3))) unsigned int*)l,
        16, 0, 0);
}

// k-interleaved fp8 row layout: within each 64B-aligned k-block, memory
// 8B-granule g holds logical k-chunk c(g) = (g>>1) + 4*(g&1); inverse
// g(c) = 2*(c&3)+(c>>2).  => 16B position p holds chunks {p, p+4}, i.e. the
// (kk=0,qd=p) and (kk=1,qd=p) fragments: one b128 read = 2 fp8 fragments.
__device__ __forceinline__ int gmem_of(int c) { return 2 * (c & 3) + (c >> 2); }

// --------------------------------------------------------------------------
// Kernel 1: fused prep (unchanged; ~10-14 us, near HBM floor).
// --------------------------------------------------------------------------
extern "C" __global__ __launch_bounds__(256) void prep(
        const float* __restrict__ W, const float* __restrict__ x,
        unsigned char* __restrict__ protos, unsigned char* __restrict__ xb,
        float* __restrict__ psq_part, float* __restrict__ x_sq) {
    __shared__ float tile[64][65];   // [d][c], +1 pad (z==2 uses [0][0..3])
    const int t = threadIdx.x;

    if (blockIdx.z == 2) {
        const int b = blockIdx.x + 32 * blockIdx.y;
        const float* xp = x + (size_t)b * IN_DIM + t * 8;
        const float4 v0 = ((const float4*)xp)[0];
        const float4 v1 = ((const float4*)xp)[1];
        uint2 pk;
        pk.x = pk4(v0.x, v0.y, v0.z, v0.w);
        pk.y = pk4(v1.x, v1.y, v1.z, v1.w);
        // t*8 elems = k-block t>>3, chunk t&7 -> interleaved granule position
        *(uint2*)(xb + (size_t)b * IN_DIM + (t >> 3) * 64 + gmem_of(t & 7) * 8) = pk;

        float s = v0.x * v0.x + v0.y * v0.y + v0.z * v0.z + v0.w * v0.w
                + v1.x * v1.x + v1.y * v1.y + v1.z * v1.z + v1.w * v1.w;
#pragma unroll
        for (int off = 32; off > 0; off >>= 1) s += __shfl_down(s, off);
        const int lane = t & 63, w = t >> 6;
        if (lane == 0) tile[0][w] = s;
        __syncthreads();
        if (t == 0) x_sq[b] = tile[0][0] + tile[0][1] + tile[0][2] + tile[0][3];
        return;
    }

    const int r  = blockIdx.z;
    const int c0 = blockIdx.x * 64;
    const int d0 = blockIdx.y * 64;
    const int g  = t >> 4;
    const int cc = (t & 15) * 4;

    const float* Wp = W + (size_t)(r * IN_DIM + d0 + g) * IN_DIM + c0 + cc;
#pragma unroll
    for (int p = 0; p < 4; ++p) {
        const float4 v = *(const float4*)(Wp + (size_t)(16 * p) * IN_DIM);
        const int dl = g + 16 * p;
        tile[dl][cc]     = v.x;
        tile[dl][cc + 1] = v.y;
        tile[dl][cc + 2] = v.z;
        tile[dl][cc + 3] = v.w;
    }
    __syncthreads();

    const int c8 = t & 7;                 // k-chunk within the 64-d tile
    const int gm = gmem_of(c8);
#pragma unroll
    for (int p = 0; p < 2; ++p) {
        const int cr = (t >> 3) + 32 * p; // c-row 0..63
        float v[8];
        float ss = 0.f;
#pragma unroll
        for (int j = 0; j < 8; ++j) {     // banks (8c8+j+cr)%32 -> 2-way, free
            v[j] = tile[8 * c8 + j][cr];
            ss += v[j] * v[j];
        }
        const int o = 2 * (c0 + cr) + r;
        uint2 pk;
        pk.x = pk4(16.f * v[0], 16.f * v[1], 16.f * v[2], 16.f * v[3]);
        pk.y = pk4(16.f * v[4], 16.f * v[5], 16.f * v[6], 16.f * v[7]);
        *(uint2*)(protos + (size_t)o * IN_DIM + d0 + gm * 8) = pk;
        ss += __shfl_xor(ss, 1);
        ss += __shfl_xor(ss, 2);
        ss += __shfl_xor(ss, 4);
        if (c8 == 0) psq_part[(size_t)blockIdx.y * OUT_DIM + o] = ss;
    }
}

// --------------------------------------------------------------------------
// Kernel 2: fp8 GEMM + epilogue.
// R11: revert R10's explicit pipeline (regressed 108.7->116.6: sched_barrier
// pins + asm waits defeat compiler scheduling, m141; cross-block TLP at
// 4 blocks/CU already hid the latency, m114). Back to the proven
// single-buffer __syncthreads structure, with ONE change:
//   B is NOT staged through LDS. Derivation: LDS B row R phys pos pr maps to
//   global Bt[(n0+R)*2048 + kh*1024 + qd*16 + it*64]; wave (kh,nh) is the
//   ONLY consumer of those bytes (kh waves read disjoint 1KB halves, nh
//   waves disjoint rows) -> zero intra-block reuse -> staging was pure
//   overhead (Common-mistake #7). bf[j] now loads global->VGPR directly;
//   4 qd-lanes cover each 64B line fully (coalesced). A keeps LDS staging
//   (2x reuse across nh waves). Per block-iter LDS traffic 40.5->24 KB,
//   staging instrs 4->2, B-frag ds_reads gone. The __syncthreads vmcnt(0)
//   drain covers the B reg-loads, so B latency hides under A latency.
// LDS 16 KB (8 KB A tile; full 16 KB reused by epilogue). 4 blocks/CU.
// --------------------------------------------------------------------------
extern "C" __global__ __launch_bounds__(256, 4) void gemm_epi(
        const unsigned char* __restrict__ A,
        const unsigned char* __restrict__ Bt,
        const float* __restrict__ x_sq,
        const float* __restrict__ psq_part,
        const float* __restrict__ bias,
        float* __restrict__ out) {
    __shared__ __align__(16) unsigned char smem[16384];
    unsigned char* lA = smem;            // 8 KB: 64 rows x 128 B

    const int lid = blockIdx.x;          // XCD swizzle: XCD k owns n-tiles [8k,8k+8)
    const int xcd = lid & 7;
    const int wi  = lid >> 3;
    const int nt  = xcd * 8 + (wi & 7);
    const int mt  = wi >> 3;
    const int m0 = mt * 64;
    const int n0 = nt * 64;

    const int t = threadIdx.x;
    // A staging: thread t owns LDS bytes [16t,16t+16) and [4096+16t,+16).
    // off -> row=off>>7, phys pos p=(off>>4)&7; logical l = p^(row&7);
    // l -> k-half l>>2 (byte l>>2 * 1024), 16B-chunk l&3 of the 64B k-block.
    const int rS = t >> 3;               // row 0..31 (2nd chunk: +32, same &7)
    const int pS = t & 7;
    const int lS = pS ^ (rS & 7);
    const size_t goff = (size_t)(lS >> 2) * 1024 + (lS & 3) * 16;
    const unsigned char* gA0 = A  + (size_t)(m0 + rS) * IN_DIM + goff;
    const unsigned char* gA1 = gA0 + (size_t)32 * IN_DIM;
    unsigned char* lAd = lA + t * 16;

    const int wave = t >> 6;
    const int lane = t & 63;
    const int kh = wave & 1;             // K-half this wave owns
    const int nh = wave >> 1;            // N-half this wave owns
    const int ln = lane & 15;
    const int qd = lane >> 4;
    const int pr = (kh * 4 + qd) ^ (ln & 7);   // phys 16B pos for A frag reads

    // direct B fragment pointer: row n0+nh*32+j*16+ln, k-half kh, chunk qd
    const unsigned char* gBf = Bt + (size_t)(n0 + nh * 32 + ln) * IN_DIM
                                  + kh * 1024 + qd * 16;

    f32x4 acc[4][2] = {};

    for (int it = 0; it < 16; ++it) {    // BK=64 per half per iter
        async16(gA0, lAd); async16(gA1, lAd + 4096);
        gA0 += 64; gA1 += 64;
        llx2 bf[2];
        bf[0] = *(const llx2*)(gBf);
        bf[1] = *(const llx2*)(gBf + (size_t)16 * IN_DIM);
        gBf += 64;
        __syncthreads();                 // vmcnt drain: A tile + B regs ready

        llx2 af[4];
#pragma unroll
        for (int i = 0; i < 4; ++i)
            af[i] = *(const llx2*)(lA + (i * 16 + ln) * 128 + pr * 16);
#pragma unroll
        for (int kk = 0; kk < 2; ++kk)
#pragma unroll
            for (int i = 0; i < 4; ++i)
#pragma unroll
                for (int j = 0; j < 2; ++j)
                    acc[i][j] = __builtin_amdgcn_mfma_f32_16x16x32_fp8_fp8(
                                    af[i][kk], bf[j][kk], acc[i][j], 0, 0, 0);
        __syncthreads();                 // reads done before next stage
    }

    // cross-K-half reduction: kh=1 waves dump acc to LDS, kh=0 waves finish.
    if (kh == 1) {
#pragma unroll
        for (int i = 0; i < 4; ++i)
#pragma unroll
            for (int j = 0; j < 2; ++j)
                *(f32x4*)(smem + nh * 8192 + (i * 2 + j) * 1024 + lane * 16) =
                    acc[i][j];
    }
    __syncthreads();
    if (kh == 0) {
#pragma unroll
        for (int j = 0; j < 2; ++j) {
            const int col = n0 + nh * 32 + j * 16 + ln;
            float pb = bias[col];
#pragma unroll
            for (int dt = 0; dt < 32; ++dt)
                pb += psq_part[(size_t)dt * OUT_DIM + col];
#pragma unroll
            for (int i = 0; i < 4; ++i) {
                const f32x4 o4 = *(const f32x4*)(smem + nh * 8192 +
                                                 (i * 2 + j) * 1024 + lane * 16);
                const int row0 = m0 + i * 16 + qd * 4;
#pragma unroll
                for (int rr = 0; rr < 4; ++rr) {
                    const int row = row0 + rr;
                    out[(size_t)row * OUT_DIM + col] =
                        0.125f * (acc[i][j][rr] + o4[rr]) - x_sq[row] - pb;
                }
            }
        }
    }
}

// --------------------------------------------------------------------------
extern "C" void kernel_launch(void* const* d_in, const int* in_sizes, int n_in,
                              void* d_out, int out_size, void* d_ws, size_t ws_size,
                              hipStream_t stream) {
    const float* x    = (const float*)d_in[0];   // [1024, 2048]
    const float* W    = (const float*)d_in[1];   // [4096, 2048]
    const float* bias = (const float*)d_in[2];   // [4096]
    float* out = (float*)d_out;

    char* ws = (char*)d_ws;
    unsigned char* protos = (unsigned char*)ws;                               // 8 MB
    unsigned char* xb     = (unsigned char*)(ws + (size_t)8 * 1024 * 1024);   // 2 MB
    float* x_sq           = (float*)(ws + (size_t)10 * 1024 * 1024);          // 4 KB
    float* psq_part       = (float*)(ws + (size_t)10 * 1024 * 1024 + 65536);  // 512 KB

    prep<<<dim3(32, 32, 3), 256, 0, stream>>>(W, x, protos, xb, psq_part, x_sq);
    gemm_epi<<<dim3(1024), 256, 0, stream>>>(xb, protos, x_sq, psq_part, bias, out);
}